// Round 1
// baseline (630.121 us; speedup 1.0000x reference)
//
#include <hip/hip_runtime.h>

#define BB 4
#define CC 64
#define HH 128
#define WW 128
#define NN (HH*WW)      // 16384
#define HP 130
#define NPP (HP*HP)     // 16900
#define NH 8
#define DD 72

// ---------------- K0: transpose w_proj [oc][ci][3][3] -> wt[ci][w][oc] ----------------
__global__ __launch_bounds__(256) void k0_wt(const float* __restrict__ wproj, float* __restrict__ wt){
    int idx = blockIdx.x*256 + threadIdx.x;      // 64*9*64 = 36864
    if (idx >= 64*9*64) return;
    int oc = idx & 63;
    int w  = (idx >> 6) % 9;
    int ci = idx / 576;
    wt[idx] = wproj[(oc*64 + ci)*9 + w];
}

// ---------------- K1: qkv = x @ w_qkv^T + b ; relu on q,k ; write padded fields -------
__global__ __launch_bounds__(256) void k1_qkv(const float* __restrict__ x,
        const float* __restrict__ wqkv, const float* __restrict__ bqkv,
        float* __restrict__ Qp, float* __restrict__ Kp, float* __restrict__ Vp){
    __shared__ float wl[64*68];   // [c][orel] stride 68 (16B-aligned rows, broadcast float4 reads)
    __shared__ float bl[64];
    const int t = threadIdx.x;
    const int gy = blockIdx.y;    // 0=q,1=k,2=v
    const int b  = blockIdx.z;
    for (int k = 0; k < 16; ++k){
        int idx = t + k*256;               // 4096
        int orel = idx >> 6, c = idx & 63;
        wl[c*68 + orel] = wqkv[(gy*64 + orel)*64 + c];
    }
    if (t < 64) bl[t] = bqkv[gy*64 + t];
    __syncthreads();
    const int pix = blockIdx.x*256 + t;
    float acc[64];
#pragma unroll
    for (int o=0;o<64;++o) acc[o]=0.f;
    const float* xb = x + (size_t)(b*64)*NN + pix;
    for (int c=0;c<64;++c){
        float xv = xb[(size_t)c*NN];
        const float4* wrow = (const float4*)(&wl[c*68]);
#pragma unroll
        for (int o4=0;o4<16;++o4){
            float4 wv = wrow[o4];
            acc[o4*4+0] += xv*wv.x;
            acc[o4*4+1] += xv*wv.y;
            acc[o4*4+2] += xv*wv.z;
            acc[o4*4+3] += xv*wv.w;
        }
    }
    const int y = pix >> 7, xx = pix & 127;
    float* dst = (gy==0) ? Qp : ((gy==1) ? Kp : Vp);
    dst += (size_t)(b*64)*NPP + (y+1)*HP + (xx+1);
    const bool dorelu = (gy < 2);
#pragma unroll
    for (int o=0;o<64;++o){
        float v = acc[o] + bl[o];
        if (dorelu) v = fmaxf(v, 0.f);
        dst[(size_t)o*NPP] = v;
    }
}

// ---------------- K2: ksum[b][h][cl*9+w] = windowed sums of Kpad ----------------------
__global__ __launch_bounds__(256) void k2_ksum(const float* __restrict__ Kp, float* __restrict__ ksum){
    const int c = blockIdx.x, b = blockIdx.y;
    const float* src = Kp + (size_t)(b*64 + c)*NPP;
    float a[3][3];
#pragma unroll
    for (int i=0;i<3;++i)
#pragma unroll
        for (int j=0;j<3;++j) a[i][j]=0.f;
    for (int idx = threadIdx.x; idx < NPP; idx += 256){
        int r = idx / HP, cc = idx - r*HP;
        float v = src[idx];
#pragma unroll
        for (int i=0;i<3;++i){
            bool fy = (unsigned)(r - i) < 128u;
#pragma unroll
            for (int j=0;j<3;++j){
                bool fx = (unsigned)(cc - j) < 128u;
                if (fy && fx) a[i][j] += v;
            }
        }
    }
    __shared__ float red[4][9];
#pragma unroll
    for (int i=0;i<3;++i)
#pragma unroll
        for (int j=0;j<3;++j){
            float v = a[i][j];
            for (int m=1;m<64;m<<=1) v += __shfl_xor(v, m, 64);
            a[i][j] = v;
        }
    int wave = threadIdx.x >> 6, lane = threadIdx.x & 63;
    if (lane == 0){
#pragma unroll
        for (int w=0;w<9;++w) red[wave][w] = a[w/3][w%3];
    }
    __syncthreads();
    if (threadIdx.x < 9){
        float s = red[0][threadIdx.x]+red[1][threadIdx.x]+red[2][threadIdx.x]+red[3][threadIdx.x];
        int h = c >> 3, cl = c & 7;
        ksum[(b*NH + h)*DD + cl*9 + threadIdx.x] = s;
    }
}

// ---------------- K3: kv[b][h][cd*9+w][ce*9+w2] = sum_n Kw * Vw2 ----------------------
__global__ __launch_bounds__(256) void k3_kv(const float* __restrict__ Kp, const float* __restrict__ Vp,
                                             float* __restrict__ kvm){
    const int cc2 = blockIdx.x;          // cd*8+ce
    const int cd = cc2 >> 3, ce = cc2 & 7;
    const int h = blockIdx.y, b = blockIdx.z;
    const float* Kc = Kp + (size_t)(b*64 + h*8 + cd)*NPP;
    const float* Vc = Vp + (size_t)(b*64 + h*8 + ce)*NPP;
    float acc[9][9];
#pragma unroll
    for (int i=0;i<9;++i)
#pragma unroll
        for (int j=0;j<9;++j) acc[i][j]=0.f;
    for (int it=0; it<64; ++it){
        int pix = threadIdx.x + it*256;
        int y = pix >> 7, xx = pix & 127;
        const float* kb = Kc + y*HP + xx;
        const float* vb = Vc + y*HP + xx;
        float kw[9], vw[9];
#pragma unroll
        for (int w=0;w<9;++w){ kw[w] = kb[(w/3)*HP + (w%3)]; vw[w] = vb[(w/3)*HP + (w%3)]; }
#pragma unroll
        for (int w=0;w<9;++w)
#pragma unroll
            for (int w2=0;w2<9;++w2) acc[w][w2] += kw[w]*vw[w2];
    }
    __shared__ float red[4][81];
#pragma unroll
    for (int w=0;w<9;++w)
#pragma unroll
        for (int w2=0;w2<9;++w2){
            float v = acc[w][w2];
            for (int m=1;m<64;m<<=1) v += __shfl_xor(v, m, 64);
            acc[w][w2] = v;
        }
    int wave = threadIdx.x >> 6, lane = threadIdx.x & 63;
    if (lane == 0){
#pragma unroll
        for (int w=0;w<9;++w)
#pragma unroll
            for (int w2=0;w2<9;++w2) red[wave][w*9+w2] = acc[w][w2];
    }
    __syncthreads();
    if (threadIdx.x < 81){
        float s = red[0][threadIdx.x]+red[1][threadIdx.x]+red[2][threadIdx.x]+red[3][threadIdx.x];
        int w = threadIdx.x / 9, w2 = threadIdx.x - w*9;
        kvm[((size_t)(b*NH + h)*DD + cd*9 + w)*DD + ce*9 + w2] = s;
    }
}

// ---------------- K4: r[b][h][n] = 1/(q_n . ksum + eps) -------------------------------
__global__ __launch_bounds__(256) void k4_r(const float* __restrict__ Qp, const float* __restrict__ ksum,
                                            float* __restrict__ rfld){
    const int h = blockIdx.y, b = blockIdx.z;
    __shared__ float ks[72];
    if (threadIdx.x < 72) ks[threadIdx.x] = ksum[(b*NH + h)*DD + threadIdx.x];
    __syncthreads();
    const int pix = blockIdx.x*256 + threadIdx.x;
    const int y = pix >> 7, xx = pix & 127;
    const float* Qb = Qp + (size_t)(b*64 + h*8)*NPP + y*HP + xx;
    float denom = 0.f;
#pragma unroll
    for (int cl=0; cl<8; ++cl){
        const float* q = Qb + (size_t)cl*NPP;
#pragma unroll
        for (int w=0; w<9; ++w){
            denom += q[(w/3)*HP + (w%3)] * ks[cl*9 + w];
        }
    }
    rfld[(size_t)(b*NH + h)*NN + pix] = 1.f/(denom + 1e-6f);
}

// ---------------- K5: numerator matvec (as 8->72ch conv with kv weights) * r, fold ----
__global__ __launch_bounds__(256) void k5_attn(const float* __restrict__ Qp, const float* __restrict__ kvm,
          const float* __restrict__ rfld, float* __restrict__ folded){
    __shared__ float Qt[8*18*20];   // [cl][r(18)][cc(18), stride 20]
    __shared__ float kvt[72*72];    // [d][e]
    __shared__ float ft[8*18*18];   // fold accumulator, halo 1 each side
    const int t = threadIdx.x;
    const int tile = blockIdx.x;    // 0..63 (8x8 tiles of 16x16)
    const int h = blockIdx.y, b = blockIdx.z;
    const int ty0 = (tile >> 3)*16, tx0 = (tile & 7)*16;

    for (int idx=t; idx<72*72; idx+=256) kvt[idx] = kvm[(size_t)(b*NH + h)*DD*DD + idx];
    const float* Qb = Qp + (size_t)(b*64 + h*8)*NPP;
    for (int idx=t; idx<8*18*18; idx+=256){
        int cl = idx / 324; int rem = idx - cl*324; int r = rem/18, cc = rem - r*18;
        Qt[cl*360 + r*20 + cc] = Qb[(size_t)cl*NPP + (ty0 + r)*HP + (tx0 + cc)];
    }
    for (int idx=t; idx<8*18*18; idx+=256) ft[idx] = 0.f;
    __syncthreads();

    const int eb = t & 7;           // output channel (head-local c')
    const int s  = t >> 3;          // strip 0..31
    const int sr = s >> 1;          // row 0..15
    const int sc = (s & 1)*8;       // col start 0 or 8

    const float* rb = rfld + (size_t)(b*NH + h)*NN + (ty0 + sr)*WW + (tx0 + sc);
    float rv[8];
#pragma unroll
    for (int p=0;p<8;++p) rv[p] = rb[p];

    float acc[9][8];
#pragma unroll
    for (int u=0;u<9;++u)
#pragma unroll
        for (int p=0;p<8;++p) acc[u][p]=0.f;

    const float* qbase  = &Qt[sr*20 + sc];
    const float* kvbase = &kvt[eb*9];
    for (int cl=0; cl<8; ++cl){
        float qw[3][10];
        const float* qc = qbase + cl*360;
#pragma unroll
        for (int i=0;i<3;++i)
#pragma unroll
            for (int q=0;q<10;++q) qw[i][q] = qc[i*20 + q];
#pragma unroll
        for (int w=0;w<9;++w){
            const int i = w/3, j = w%3;
            const float* kr = kvbase + (cl*9 + w)*72;
            float kv9[9];
#pragma unroll
            for (int u=0;u<9;++u) kv9[u] = kr[u];
#pragma unroll
            for (int u=0;u<9;++u)
#pragma unroll
                for (int p=0;p<8;++p)
                    acc[u][p] += kv9[u]*qw[i][p+j];
        }
    }
    // scatter-fold into LDS (offset (i'-1, j'-1); ft origin = tile origin - 1)
    float* ftc = &ft[eb*324];
#pragma unroll
    for (int u=0;u<9;++u){
        const int iu = u/3, ju = u%3;
#pragma unroll
        for (int p=0;p<8;++p){
            atomicAdd(&ftc[(sr + iu)*18 + (sc + p + ju)], acc[u][p]*rv[p]);
        }
    }
    __syncthreads();
    // write out: inner core exclusive, rim via global atomics
    for (int idx=t; idx<8*18*18; idx+=256){
        int cl = idx / 324; int rem = idx - cl*324; int r = rem/18, cc = rem - r*18;
        int iy = ty0 - 1 + r, ix = tx0 - 1 + cc;
        if ((unsigned)iy < 128u && (unsigned)ix < 128u){
            float v = ft[idx];
            float* dst = &folded[(size_t)(b*64 + h*8 + cl)*NN + iy*WW + ix];
            if (r >= 2 && r < 16 && cc >= 2 && cc < 16) *dst = v;
            else atomicAdd(dst, v);
        }
    }
}

// ---------------- K6: y = conv3x3(folded/counts, w_proj) + b_proj ---------------------
__global__ __launch_bounds__(256) void k6_conv(const float* __restrict__ folded, const float* __restrict__ wt,
         const float* __restrict__ bproj, float* __restrict__ out){
    __shared__ float ut[8*18*12];   // [cil][rr(18)][cc(10), stride 12]
    const int t = threadIdx.x;
    const int tile = blockIdx.x;    // 0..127 : 8 row-tiles (16) x 16 col-tiles (8)
    const int b = blockIdx.y;
    const int ty0 = (tile >> 4)*16, tx0 = (tile & 15)*8;
    const int ocb = t & 15;         // 4 output channels
    const int s   = t >> 4;         // row 0..15
    float acc[4][8];
#pragma unroll
    for (int ol=0;ol<4;++ol)
#pragma unroll
        for (int p=0;p<8;++p) acc[ol][p]=0.f;
    const float4 bias = *(const float4*)(&bproj[ocb*4]);

    for (int ch=0; ch<8; ++ch){     // ci chunks of 8
        __syncthreads();
        for (int idx=t; idx<8*18*10; idx+=256){
            int cil = idx / 180; int rem = idx - cil*180; int rr = rem/10, cc = rem - rr*10;
            int iy = ty0 - 1 + rr, ix = tx0 - 1 + cc;
            float v = 0.f;
            if ((unsigned)iy < 128u && (unsigned)ix < 128u){
                int ry = 3 - (iy==0) - (iy==127);
                int rx = 3 - (ix==0) - (ix==127);
                v = folded[(size_t)(b*64 + ch*8 + cil)*NN + iy*WW + ix] / (float)(ry*rx);
            }
            ut[cil*216 + rr*12 + cc] = v;
        }
        __syncthreads();
        for (int cil=0; cil<8; ++cil){
            const int ci = ch*8 + cil;
            float uw[3][10];
            const float* ub = &ut[cil*216 + s*12];
#pragma unroll
            for (int dy=0;dy<3;++dy)
#pragma unroll
                for (int q=0;q<10;++q) uw[dy][q] = ub[dy*12 + q];
#pragma unroll
            for (int w=0;w<9;++w){
                const int dy = w/3, dx = w%3;
                float4 wv = *(const float4*)(&wt[(ci*9 + w)*64 + ocb*4]);
#pragma unroll
                for (int p=0;p<8;++p){
                    float u = uw[dy][p+dx];
                    acc[0][p] += wv.x*u;
                    acc[1][p] += wv.y*u;
                    acc[2][p] += wv.z*u;
                    acc[3][p] += wv.w*u;
                }
            }
        }
    }
    const int y = ty0 + s;
#pragma unroll
    for (int ol=0;ol<4;++ol){
        const int oc = ocb*4 + ol;
        float* dst = &out[(size_t)(b*64 + oc)*NN + y*WW + tx0];
        float bv = (ol==0)?bias.x:(ol==1)?bias.y:(ol==2)?bias.z:bias.w;
#pragma unroll
        for (int p=0;p<8;++p) dst[p] = acc[ol][p] + bv;
    }
}

extern "C" void kernel_launch(void* const* d_in, const int* in_sizes, int n_in,
                              void* d_out, int out_size, void* d_ws, size_t ws_size,
                              hipStream_t stream) {
    const float* x     = (const float*)d_in[0];
    const float* wqkv  = (const float*)d_in[1];
    const float* bqkv  = (const float*)d_in[2];
    const float* wproj = (const float*)d_in[3];
    const float* bproj = (const float*)d_in[4];
    float* out = (float*)d_out;
    float* ws  = (float*)d_ws;

    const size_t szQ = (size_t)BB*CC*NPP;       // 4,326,400 floats per padded field
    float* Qp     = ws;
    float* Kp     = Qp + szQ;
    float* Vp     = Kp + szQ;
    float* folded = Vp + szQ;                    // B*C*N
    float* kvm    = folded + (size_t)BB*CC*NN;   // B*8*72*72
    float* rfld   = kvm + (size_t)BB*NH*DD*DD;   // B*8*N
    float* ksum   = rfld + (size_t)BB*NH*NN;     // B*8*72
    float* wt     = ksum + (size_t)BB*NH*DD;     // 64*9*64
    // total ~17.9M floats = 71.6 MB of ws

    // zero padded QKV fields + fold buffer (contiguous prefix)
    hipMemsetAsync(ws, 0, (3*szQ + (size_t)BB*CC*NN)*sizeof(float), stream);

    k0_wt  <<<dim3(144),      256, 0, stream>>>(wproj, wt);
    k1_qkv <<<dim3(64, 3, 4), 256, 0, stream>>>(x, wqkv, bqkv, Qp, Kp, Vp);
    k2_ksum<<<dim3(64, 4),    256, 0, stream>>>(Kp, ksum);
    k3_kv  <<<dim3(64, 8, 4), 256, 0, stream>>>(Kp, Vp, kvm);
    k4_r   <<<dim3(64, 8, 4), 256, 0, stream>>>(Qp, ksum, rfld);
    k5_attn<<<dim3(64, 8, 4), 256, 0, stream>>>(Qp, kvm, rfld, folded);
    k6_conv<<<dim3(128, 4),   256, 0, stream>>>(folded, wt, bproj, out);
}

// Round 2
// 472.077 us; speedup vs baseline: 1.3348x; 1.3348x over previous
//
#include <hip/hip_runtime.h>

#define BB 4
#define CC 64
#define HH 128
#define WW 128
#define NN (HH*WW)      // 16384
#define HP 130
#define NPP (HP*HP)     // 16900 (1-pad fields: K, V, r)
#define HP2 132
#define NPP2 (HP2*HP2)  // 17424 (2-pad field: Q)
#define NH 8
#define DD 72

// ---------------- K0: transpose w_proj [oc][ci][3][3] -> wt[ci][w][oc] ----------------
__global__ __launch_bounds__(256) void k0_wt(const float* __restrict__ wproj, float* __restrict__ wt){
    int idx = blockIdx.x*256 + threadIdx.x;      // 64*9*64 = 36864
    if (idx >= 64*9*64) return;
    int oc = idx & 63;
    int w  = (idx >> 6) % 9;
    int ci = idx / 576;
    wt[idx] = wproj[(oc*64 + ci)*9 + w];
}

// ---------------- K1: qkv = x @ w_qkv^T + b ; relu on q,k ; write padded fields -------
// Q gets a 2-pixel zero pad (132x132), K/V a 1-pixel pad (130x130).
__global__ __launch_bounds__(256) void k1_qkv(const float* __restrict__ x,
        const float* __restrict__ wqkv, const float* __restrict__ bqkv,
        float* __restrict__ Qp, float* __restrict__ Kp, float* __restrict__ Vp){
    __shared__ float wl[64*68];   // [c][orel] stride 68
    __shared__ float bl[64];
    const int t = threadIdx.x;
    const int gy = blockIdx.y;    // 0=q,1=k,2=v
    const int b  = blockIdx.z;
    for (int k = 0; k < 16; ++k){
        int idx = t + k*256;               // 4096
        int orel = idx >> 6, c = idx & 63;
        wl[c*68 + orel] = wqkv[(gy*64 + orel)*64 + c];
    }
    if (t < 64) bl[t] = bqkv[gy*64 + t];
    __syncthreads();
    const int pix = blockIdx.x*256 + t;
    float acc[64];
#pragma unroll
    for (int o=0;o<64;++o) acc[o]=0.f;
    const float* xb = x + (size_t)(b*64)*NN + pix;
    for (int c=0;c<64;++c){
        float xv = xb[(size_t)c*NN];
        const float4* wrow = (const float4*)(&wl[c*68]);
#pragma unroll
        for (int o4=0;o4<16;++o4){
            float4 wv = wrow[o4];
            acc[o4*4+0] += xv*wv.x;
            acc[o4*4+1] += xv*wv.y;
            acc[o4*4+2] += xv*wv.z;
            acc[o4*4+3] += xv*wv.w;
        }
    }
    const int y = pix >> 7, xx = pix & 127;
    float* dst; size_t cstride;
    if (gy == 0){ dst = Qp + (size_t)(b*64)*NPP2 + (y+2)*HP2 + (xx+2); cstride = NPP2; }
    else { dst = ((gy==1)?Kp:Vp) + (size_t)(b*64)*NPP + (y+1)*HP + (xx+1); cstride = NPP; }
    const bool dorelu = (gy < 2);
#pragma unroll
    for (int o=0;o<64;++o){
        float v = acc[o] + bl[o];
        if (dorelu) v = fmaxf(v, 0.f);
        dst[(size_t)o*cstride] = v;
    }
}

// ---------------- K2: ksum[b][h][cl*9+w] = windowed sums of Kpad ----------------------
__global__ __launch_bounds__(256) void k2_ksum(const float* __restrict__ Kp, float* __restrict__ ksum){
    const int c = blockIdx.x, b = blockIdx.y;
    const float* src = Kp + (size_t)(b*64 + c)*NPP;
    float a[3][3];
#pragma unroll
    for (int i=0;i<3;++i)
#pragma unroll
        for (int j=0;j<3;++j) a[i][j]=0.f;
    for (int idx = threadIdx.x; idx < NPP; idx += 256){
        int r = idx / HP, cc = idx - r*HP;
        float v = src[idx];
#pragma unroll
        for (int i=0;i<3;++i){
            bool fy = (unsigned)(r - i) < 128u;
#pragma unroll
            for (int j=0;j<3;++j){
                bool fx = (unsigned)(cc - j) < 128u;
                if (fy && fx) a[i][j] += v;
            }
        }
    }
    __shared__ float red[4][9];
#pragma unroll
    for (int i=0;i<3;++i)
#pragma unroll
        for (int j=0;j<3;++j){
            float v = a[i][j];
            for (int m=1;m<64;m<<=1) v += __shfl_xor(v, m, 64);
            a[i][j] = v;
        }
    int wave = threadIdx.x >> 6, lane = threadIdx.x & 63;
    if (lane == 0){
#pragma unroll
        for (int w=0;w<9;++w) red[wave][w] = a[w/3][w%3];
    }
    __syncthreads();
    if (threadIdx.x < 9){
        float s = red[0][threadIdx.x]+red[1][threadIdx.x]+red[2][threadIdx.x]+red[3][threadIdx.x];
        int h = c >> 3, cl = c & 7;
        ksum[(b*NH + h)*DD + cl*9 + threadIdx.x] = s;
    }
}

// ---------------- K3: kv[b][h][cd*9+w][ce*9+w2] = sum_n Kw * Vw2 ----------------------
__global__ __launch_bounds__(256) void k3_kv(const float* __restrict__ Kp, const float* __restrict__ Vp,
                                             float* __restrict__ kvm){
    const int cc2 = blockIdx.x;          // cd*8+ce
    const int cd = cc2 >> 3, ce = cc2 & 7;
    const int h = blockIdx.y, b = blockIdx.z;
    const float* Kc = Kp + (size_t)(b*64 + h*8 + cd)*NPP;
    const float* Vc = Vp + (size_t)(b*64 + h*8 + ce)*NPP;
    float acc[9][9];
#pragma unroll
    for (int i=0;i<9;++i)
#pragma unroll
        for (int j=0;j<9;++j) acc[i][j]=0.f;
    for (int it=0; it<64; ++it){
        int pix = threadIdx.x + it*256;
        int y = pix >> 7, xx = pix & 127;
        const float* kb = Kc + y*HP + xx;
        const float* vb = Vc + y*HP + xx;
        float kw[9], vw[9];
#pragma unroll
        for (int w=0;w<9;++w){ kw[w] = kb[(w/3)*HP + (w%3)]; vw[w] = vb[(w/3)*HP + (w%3)]; }
#pragma unroll
        for (int w=0;w<9;++w)
#pragma unroll
            for (int w2=0;w2<9;++w2) acc[w][w2] += kw[w]*vw[w2];
    }
    __shared__ float red[4][81];
#pragma unroll
    for (int w=0;w<9;++w)
#pragma unroll
        for (int w2=0;w2<9;++w2){
            float v = acc[w][w2];
            for (int m=1;m<64;m<<=1) v += __shfl_xor(v, m, 64);
            acc[w][w2] = v;
        }
    int wave = threadIdx.x >> 6, lane = threadIdx.x & 63;
    if (lane == 0){
#pragma unroll
        for (int w=0;w<9;++w)
#pragma unroll
            for (int w2=0;w2<9;++w2) red[wave][w*9+w2] = acc[w][w2];
    }
    __syncthreads();
    if (threadIdx.x < 81){
        float s = red[0][threadIdx.x]+red[1][threadIdx.x]+red[2][threadIdx.x]+red[3][threadIdx.x];
        int w = threadIdx.x / 9, w2 = threadIdx.x - w*9;
        kvm[((size_t)(b*NH + h)*DD + cd*9 + w)*DD + ce*9 + w2] = s;
    }
}

// ---------------- K4: r[b][h][pad(y,x)] = 1/(q . ksum + eps), zero-padded 130x130 -----
__global__ __launch_bounds__(256) void k4_r(const float* __restrict__ Qp, const float* __restrict__ ksum,
                                            float* __restrict__ rfp){
    const int h = blockIdx.y, b = blockIdx.z;
    __shared__ float ks[72];
    if (threadIdx.x < 72) ks[threadIdx.x] = ksum[(b*NH + h)*DD + threadIdx.x];
    __syncthreads();
    const int pix = blockIdx.x*256 + threadIdx.x;
    const int y = pix >> 7, xx = pix & 127;
    // image pixel (y,x): 3x3 window = image rows y-1..y+1 = 2-pad rows y+1..y+3
    const float* Qb = Qp + (size_t)(b*64 + h*8)*NPP2 + (y+1)*HP2 + (xx+1);
    float denom = 0.f;
#pragma unroll
    for (int cl=0; cl<8; ++cl){
        const float* q = Qb + (size_t)cl*NPP2;
#pragma unroll
        for (int w=0; w<9; ++w){
            denom += q[(w/3)*HP2 + (w%3)] * ks[cl*9 + w];
        }
    }
    rfp[(size_t)(b*NH + h)*NPP + (y+1)*HP + (xx+1)] = 1.f/(denom + 1e-6f);
}

// ---------------- K5: fused numerator + fold as a direct gather (no atomics) ----------
// folded[c][m] = sum_u r[m-Du] * sum_{cl,w} Q[cl][m + (Dw-Du)] * kv[cl*9+w][c*9+u]
__global__ __launch_bounds__(256) void k5_attn(const float* __restrict__ Qp, const float* __restrict__ kvm,
          const float* __restrict__ rfp, float* __restrict__ folded){
    __shared__ __align__(16) float kvt[72*100];   // [e][cl*12+w], padded strides
    __shared__ __align__(16) float Qt[8*20*24];   // [cl][20 rows][20 cols, stride 24], origin (ty0-2,tx0-2) in image coords
    __shared__ __align__(16) float rt[18*20];     // [18 rows][18 cols, stride 20], origin (ty0-1,tx0-1)
    const int t = threadIdx.x;
    const int tile = blockIdx.x;    // 8x8 tiles of 16x16
    const int h = blockIdx.y, b = blockIdx.z;
    const int ty0 = (tile >> 3)*16, tx0 = (tile & 7)*16;

    // stage kv transposed: kvt[e][cl*12+w] = kvm[(cl*9+w)*72 + e]
    const float* kvg = kvm + (size_t)(b*NH + h)*DD*DD;
    for (int idx=t; idx<DD*DD; idx+=256){
        int d = idx / 72, e = idx - d*72;
        int cl = d / 9, w = d - cl*9;
        kvt[e*100 + cl*12 + w] = kvg[idx];
    }
    // stage Q halo(+-2): padded-Q row ty0+r corresponds to image row ty0+r-2
    const float* Qb = Qp + (size_t)(b*64 + h*8)*NPP2 + (size_t)ty0*HP2 + tx0;
    for (int idx=t; idx<8*20*20; idx+=256){
        int cl = idx / 400; int rem = idx - cl*400; int r = rem/20, cc = rem - r*20;
        Qt[cl*480 + r*24 + cc] = Qb[(size_t)cl*NPP2 + r*HP2 + cc];
    }
    // stage r halo(+-1): padded-r row ty0+rr = image row ty0+rr-1
    const float* rg = rfp + (size_t)(b*NH + h)*NPP + (size_t)ty0*HP + tx0;
    for (int idx=t; idx<18*18; idx+=256){
        int rr = idx / 18, cc = idx - rr*18;
        rt[rr*20 + cc] = rg[rr*HP + cc];
    }
    __syncthreads();

    const int c  = t & 7;           // output channel (head-local)
    const int s  = t >> 3;          // strip 0..31
    const int sr = s >> 1;          // row 0..15
    const int sc = (s & 1)*8;       // col start 0 or 8

    float acc[9][8];
#pragma unroll
    for (int u=0;u<9;++u)
#pragma unroll
        for (int p=0;p<8;++p) acc[u][p]=0.f;

    for (int cl=0; cl<8; ++cl){
        // Q window: rows sr..sr+4, cols sc..sc+11 of Qt (covers all (Dw-Du)+pixel offsets)
        float qw[5][12];
        const float* qb = &Qt[cl*480 + sr*24 + sc];
#pragma unroll
        for (int rr=0; rr<5; ++rr){
            float4 a0 = *(const float4*)(qb + rr*24);
            float4 a1 = *(const float4*)(qb + rr*24 + 4);
            float4 a2 = *(const float4*)(qb + rr*24 + 8);
            qw[rr][0]=a0.x; qw[rr][1]=a0.y; qw[rr][2]=a0.z; qw[rr][3]=a0.w;
            qw[rr][4]=a1.x; qw[rr][5]=a1.y; qw[rr][6]=a1.z; qw[rr][7]=a1.w;
            qw[rr][8]=a2.x; qw[rr][9]=a2.y; qw[rr][10]=a2.z; qw[rr][11]=a2.w;
        }
#pragma unroll
        for (int u=0; u<9; ++u){
            const float* kr = &kvt[(c*9 + u)*100 + cl*12];
            float4 k0 = *(const float4*)kr;
            float4 k1 = *(const float4*)(kr + 4);
            float k8 = kr[8];
            float kw[9] = {k0.x,k0.y,k0.z,k0.w,k1.x,k1.y,k1.z,k1.w,k8};
            const int iu = u/3, ju = u - iu*3;
#pragma unroll
            for (int w=0; w<9; ++w){
                const int rr = (w/3) - iu + 2;
                const int cc = (w%3) - ju + 2;
#pragma unroll
                for (int p=0;p<8;++p)
                    acc[u][p] += qw[rr][cc+p] * kw[w];
            }
        }
    }
    // r-weighted fold-gather: out[p] = sum_u acc[u][p] * r[(sr+2-iu, sc+p+2-ju) in rt coords]
    float rw[3][10];
    const float* rb = &rt[sr*20 + sc];
#pragma unroll
    for (int rr=0; rr<3; ++rr){
        float4 a0 = *(const float4*)(rb + rr*20);
        float4 a1 = *(const float4*)(rb + rr*20 + 4);
        float2 a2 = *(const float2*)(rb + rr*20 + 8);
        rw[rr][0]=a0.x; rw[rr][1]=a0.y; rw[rr][2]=a0.z; rw[rr][3]=a0.w;
        rw[rr][4]=a1.x; rw[rr][5]=a1.y; rw[rr][6]=a1.z; rw[rr][7]=a1.w;
        rw[rr][8]=a2.x; rw[rr][9]=a2.y;
    }
    float out[8];
#pragma unroll
    for (int p=0;p<8;++p) out[p]=0.f;
#pragma unroll
    for (int u=0; u<9; ++u){
        const int iu = u/3, ju = u - iu*3;
#pragma unroll
        for (int p=0;p<8;++p)
            out[p] += acc[u][p] * rw[2-iu][2-ju+p];
    }
    float* dst = &folded[(size_t)(b*64 + h*8 + c)*NN + (ty0+sr)*WW + tx0 + sc];
#pragma unroll
    for (int p=0;p<8;++p) dst[p] = out[p];
}

// ---------------- K6: y = conv3x3(folded/counts, w_proj) + b_proj ---------------------
__global__ __launch_bounds__(256) void k6_conv(const float* __restrict__ folded, const float* __restrict__ wt,
         const float* __restrict__ bproj, float* __restrict__ out){
    __shared__ float ut[8*18*12];   // [cil][rr(18)][cc(10), stride 12]
    const int t = threadIdx.x;
    const int tile = blockIdx.x;    // 0..127 : 8 row-tiles (16) x 16 col-tiles (8)
    const int b = blockIdx.y;
    const int ty0 = (tile >> 4)*16, tx0 = (tile & 15)*8;
    const int ocb = t & 15;         // 4 output channels
    const int s   = t >> 4;         // row 0..15
    float acc[4][8];
#pragma unroll
    for (int ol=0;ol<4;++ol)
#pragma unroll
        for (int p=0;p<8;++p) acc[ol][p]=0.f;
    const float4 bias = *(const float4*)(&bproj[ocb*4]);

    for (int ch=0; ch<8; ++ch){     // ci chunks of 8
        __syncthreads();
        for (int idx=t; idx<8*18*10; idx+=256){
            int cil = idx / 180; int rem = idx - cil*180; int rr = rem/10, cc = rem - rr*10;
            int iy = ty0 - 1 + rr, ix = tx0 - 1 + cc;
            float v = 0.f;
            if ((unsigned)iy < 128u && (unsigned)ix < 128u){
                int ry = 3 - (iy==0) - (iy==127);
                int rx = 3 - (ix==0) - (ix==127);
                v = folded[(size_t)(b*64 + ch*8 + cil)*NN + iy*WW + ix] / (float)(ry*rx);
            }
            ut[cil*216 + rr*12 + cc] = v;
        }
        __syncthreads();
        for (int cil=0; cil<8; ++cil){
            const int ci = ch*8 + cil;
            float uw[3][10];
            const float* ub = &ut[cil*216 + s*12];
#pragma unroll
            for (int dy=0;dy<3;++dy)
#pragma unroll
                for (int q=0;q<10;++q) uw[dy][q] = ub[dy*12 + q];
#pragma unroll
            for (int w=0;w<9;++w){
                const int dy = w/3, dx = w%3;
                float4 wv = *(const float4*)(&wt[(ci*9 + w)*64 + ocb*4]);
#pragma unroll
                for (int p=0;p<8;++p){
                    float u = uw[dy][p+dx];
                    acc[0][p] += wv.x*u;
                    acc[1][p] += wv.y*u;
                    acc[2][p] += wv.z*u;
                    acc[3][p] += wv.w*u;
                }
            }
        }
    }
    const int y = ty0 + s;
#pragma unroll
    for (int ol=0;ol<4;++ol){
        const int oc = ocb*4 + ol;
        float* dst = &out[(size_t)(b*64 + oc)*NN + y*WW + tx0];
        float bv = (ol==0)?bias.x:(ol==1)?bias.y:(ol==2)?bias.z:bias.w;
#pragma unroll
        for (int p=0;p<8;++p) dst[p] = acc[ol][p] + bv;
    }
}

extern "C" void kernel_launch(void* const* d_in, const int* in_sizes, int n_in,
                              void* d_out, int out_size, void* d_ws, size_t ws_size,
                              hipStream_t stream) {
    const float* x     = (const float*)d_in[0];
    const float* wqkv  = (const float*)d_in[1];
    const float* bqkv  = (const float*)d_in[2];
    const float* wproj = (const float*)d_in[3];
    const float* bproj = (const float*)d_in[4];
    float* out = (float*)d_out;
    float* ws  = (float*)d_ws;

    const size_t szQ2 = (size_t)BB*CC*NPP2;      // 4,460,544 floats (2-pad Q)
    const size_t szF  = (size_t)BB*CC*NPP;       // 4,326,400 floats (1-pad K/V)
    const size_t szR  = (size_t)BB*NH*NPP;       // 540,800 floats (1-pad r)
    float* Qp2    = ws;
    float* Kp     = Qp2 + szQ2;
    float* Vp     = Kp + szF;
    float* rfp    = Vp + szF;
    float* folded = rfp + szR;                   // B*C*N (written exclusively, no zeroing)
    float* kvm    = folded + (size_t)BB*CC*NN;   // B*8*72*72
    float* ksum   = kvm + (size_t)BB*NH*DD*DD;   // B*8*72
    float* wt     = ksum + (size_t)BB*NH*DD;     // 64*9*64
    // total ~17.9M floats = ~71.5 MB of ws

    // zero the zero-padded fields (contiguous prefix): Qp2, Kp, Vp, rfp
    hipMemsetAsync(ws, 0, (szQ2 + 2*szF + szR)*sizeof(float), stream);

    k0_wt  <<<dim3(144),      256, 0, stream>>>(wproj, wt);
    k1_qkv <<<dim3(64, 3, 4), 256, 0, stream>>>(x, wqkv, bqkv, Qp2, Kp, Vp);
    k2_ksum<<<dim3(64, 4),    256, 0, stream>>>(Kp, ksum);
    k3_kv  <<<dim3(64, 8, 4), 256, 0, stream>>>(Kp, Vp, kvm);
    k4_r   <<<dim3(64, 8, 4), 256, 0, stream>>>(Qp2, ksum, rfp);
    k5_attn<<<dim3(64, 8, 4), 256, 0, stream>>>(Qp2, kvm, rfp, folded);
    k6_conv<<<dim3(128, 4),   256, 0, stream>>>(folded, wt, bproj, out);
}

// Round 3
// 416.507 us; speedup vs baseline: 1.5129x; 1.1334x over previous
//
#include <hip/hip_runtime.h>

#define BB 4
#define CC 64
#define HH 128
#define WW 128
#define NN (HH*WW)      // 16384
#define HP 130
#define NPP (HP*HP)     // 16900 (1-pad fields: K, V, r)
#define HP2 132
#define NPP2 (HP2*HP2)  // 17424 (2-pad field: Q)
#define NH 8
#define DD 72

// ---------------- K0: transpose w_proj [oc][ci][3][3] -> wt[ci][w][oc] ----------------
__global__ __launch_bounds__(256) void k0_wt(const float* __restrict__ wproj, float* __restrict__ wt){
    int idx = blockIdx.x*256 + threadIdx.x;      // 64*9*64 = 36864
    if (idx >= 64*9*64) return;
    int oc = idx & 63;
    int w  = (idx >> 6) % 9;
    int ci = idx / 576;
    wt[idx] = wproj[(oc*64 + ci)*9 + w];
}

// ---------------- K1: qkv = x @ w_qkv^T + b ; relu on q,k ; write padded fields -------
__global__ __launch_bounds__(256) void k1_qkv(const float* __restrict__ x,
        const float* __restrict__ wqkv, const float* __restrict__ bqkv,
        float* __restrict__ Qp, float* __restrict__ Kp, float* __restrict__ Vp){
    __shared__ float wl[64*68];   // [c][orel] stride 68
    __shared__ float bl[64];
    const int t = threadIdx.x;
    const int gy = blockIdx.y;    // 0=q,1=k,2=v
    const int b  = blockIdx.z;
    for (int k = 0; k < 16; ++k){
        int idx = t + k*256;               // 4096
        int orel = idx >> 6, c = idx & 63;
        wl[c*68 + orel] = wqkv[(gy*64 + orel)*64 + c];
    }
    if (t < 64) bl[t] = bqkv[gy*64 + t];
    __syncthreads();
    const int pix = blockIdx.x*256 + t;
    float acc[64];
#pragma unroll
    for (int o=0;o<64;++o) acc[o]=0.f;
    const float* xb = x + (size_t)(b*64)*NN + pix;
    for (int c=0;c<64;++c){
        float xv = xb[(size_t)c*NN];
        const float4* wrow = (const float4*)(&wl[c*68]);
#pragma unroll
        for (int o4=0;o4<16;++o4){
            float4 wv = wrow[o4];
            acc[o4*4+0] += xv*wv.x;
            acc[o4*4+1] += xv*wv.y;
            acc[o4*4+2] += xv*wv.z;
            acc[o4*4+3] += xv*wv.w;
        }
    }
    const int y = pix >> 7, xx = pix & 127;
    float* dst; size_t cstride;
    if (gy == 0){ dst = Qp + (size_t)(b*64)*NPP2 + (y+2)*HP2 + (xx+2); cstride = NPP2; }
    else { dst = ((gy==1)?Kp:Vp) + (size_t)(b*64)*NPP + (y+1)*HP + (xx+1); cstride = NPP; }
    const bool dorelu = (gy < 2);
#pragma unroll
    for (int o=0;o<64;++o){
        float v = acc[o] + bl[o];
        if (dorelu) v = fmaxf(v, 0.f);
        dst[(size_t)o*cstride] = v;
    }
}

// ---------------- K2: ksum[b][h][cl*9+w] = windowed sums of Kpad ----------------------
__global__ __launch_bounds__(256) void k2_ksum(const float* __restrict__ Kp, float* __restrict__ ksum){
    const int c = blockIdx.x, b = blockIdx.y;
    const float* src = Kp + (size_t)(b*64 + c)*NPP;
    float a[3][3];
#pragma unroll
    for (int i=0;i<3;++i)
#pragma unroll
        for (int j=0;j<3;++j) a[i][j]=0.f;
    for (int idx = threadIdx.x; idx < NPP; idx += 256){
        int r = idx / HP, cc = idx - r*HP;
        float v = src[idx];
#pragma unroll
        for (int i=0;i<3;++i){
            bool fy = (unsigned)(r - i) < 128u;
#pragma unroll
            for (int j=0;j<3;++j){
                bool fx = (unsigned)(cc - j) < 128u;
                if (fy && fx) a[i][j] += v;
            }
        }
    }
    __shared__ float red[4][9];
#pragma unroll
    for (int i=0;i<3;++i)
#pragma unroll
        for (int j=0;j<3;++j){
            float v = a[i][j];
            for (int m=1;m<64;m<<=1) v += __shfl_xor(v, m, 64);
            a[i][j] = v;
        }
    int wave = threadIdx.x >> 6, lane = threadIdx.x & 63;
    if (lane == 0){
#pragma unroll
        for (int w=0;w<9;++w) red[wave][w] = a[w/3][w%3];
    }
    __syncthreads();
    if (threadIdx.x < 9){
        float s = red[0][threadIdx.x]+red[1][threadIdx.x]+red[2][threadIdx.x]+red[3][threadIdx.x];
        int h = c >> 3, cl = c & 7;
        ksum[(b*NH + h)*DD + cl*9 + threadIdx.x] = s;
    }
}

// ---------------- K3: kvT2[e][cl*12+w] = sum_n Kunf[cl*9+w,n] * Vunf[e,n] -------------
// Row stride 96 (16B-aligned 12-float cl-chunks) for wave-uniform scalar reads in K5.
__global__ __launch_bounds__(256) void k3_kv(const float* __restrict__ Kp, const float* __restrict__ Vp,
                                             float* __restrict__ kvT2){
    const int cc2 = blockIdx.x;          // cd*8+ce
    const int cd = cc2 >> 3, ce = cc2 & 7;
    const int h = blockIdx.y, b = blockIdx.z;
    const float* Kc = Kp + (size_t)(b*64 + h*8 + cd)*NPP;
    const float* Vc = Vp + (size_t)(b*64 + h*8 + ce)*NPP;
    float acc[9][9];
#pragma unroll
    for (int i=0;i<9;++i)
#pragma unroll
        for (int j=0;j<9;++j) acc[i][j]=0.f;
    for (int it=0; it<64; ++it){
        int pix = threadIdx.x + it*256;
        int y = pix >> 7, xx = pix & 127;
        const float* kb = Kc + y*HP + xx;
        const float* vb = Vc + y*HP + xx;
        float kw[9], vw[9];
#pragma unroll
        for (int w=0;w<9;++w){ kw[w] = kb[(w/3)*HP + (w%3)]; vw[w] = vb[(w/3)*HP + (w%3)]; }
#pragma unroll
        for (int w=0;w<9;++w)
#pragma unroll
            for (int w2=0;w2<9;++w2) acc[w][w2] += kw[w]*vw[w2];
    }
    __shared__ float red[4][81];
#pragma unroll
    for (int w=0;w<9;++w)
#pragma unroll
        for (int w2=0;w2<9;++w2){
            float v = acc[w][w2];
            for (int m=1;m<64;m<<=1) v += __shfl_xor(v, m, 64);
            acc[w][w2] = v;
        }
    int wave = threadIdx.x >> 6, lane = threadIdx.x & 63;
    if (lane == 0){
#pragma unroll
        for (int w=0;w<9;++w)
#pragma unroll
            for (int w2=0;w2<9;++w2) red[wave][w*9+w2] = acc[w][w2];
    }
    __syncthreads();
    if (threadIdx.x < 81){
        float s = red[0][threadIdx.x]+red[1][threadIdx.x]+red[2][threadIdx.x]+red[3][threadIdx.x];
        int w = threadIdx.x / 9, w2 = threadIdx.x - w*9;   // d = cd*9+w, e = ce*9+w2
        kvT2[((size_t)(b*NH + h)*DD + ce*9 + w2)*96 + cd*12 + w] = s;
    }
}

// ---------------- K4: r[b][h][pad(y,x)] = 1/(q . ksum + eps), zero-padded 130x130 -----
__global__ __launch_bounds__(256) void k4_r(const float* __restrict__ Qp, const float* __restrict__ ksum,
                                            float* __restrict__ rfp){
    const int h = blockIdx.y, b = blockIdx.z;
    __shared__ float ks[72];
    if (threadIdx.x < 72) ks[threadIdx.x] = ksum[(b*NH + h)*DD + threadIdx.x];
    __syncthreads();
    const int pix = blockIdx.x*256 + threadIdx.x;
    const int y = pix >> 7, xx = pix & 127;
    const float* Qb = Qp + (size_t)(b*64 + h*8)*NPP2 + (y+1)*HP2 + (xx+1);
    float denom = 0.f;
#pragma unroll
    for (int cl=0; cl<8; ++cl){
        const float* q = Qb + (size_t)cl*NPP2;
#pragma unroll
        for (int w=0; w<9; ++w){
            denom += q[(w/3)*HP2 + (w%3)] * ks[cl*9 + w];
        }
    }
    rfp[(size_t)(b*NH + h)*NPP + (y+1)*HP + (xx+1)] = 1.f/(denom + 1e-6f);
}

// ---------------- K5: fused numerator + fold, wave-per-channel, kv via scalar loads ---
// folded[c][m] = sum_u r[m-Du] * sum_{cl,w} Q[cl][m + (Dw-Du)] * kv[cl*9+w][c*9+u]
// Block = 512 threads = 8 waves; wave w owns channel c=w (wave-uniform -> kv reads on
// the scalar/L1 pipe, zero LDS cost). Each lane computes a 1x4 pixel strip.
__global__ __launch_bounds__(512) void k5_attn(const float* __restrict__ Qp, const float* __restrict__ kvT2,
          const float* __restrict__ rfp, float* __restrict__ folded){
    __shared__ __align__(16) float Qt[8*20*20];   // [cl][20 rows][20 cols], origin (ty0-2,tx0-2)
    __shared__ __align__(16) float rt[18*20];     // [18 rows][stride 20], origin (ty0-1,tx0-1)
    const int t = threadIdx.x;
    const int tile = blockIdx.x;    // 8x8 tiles of 16x16
    const int h = blockIdx.y, b = blockIdx.z;
    const int ty0 = (tile >> 3)*16, tx0 = (tile & 7)*16;

    // stage Q halo(+-2)
    const float* Qb = Qp + (size_t)(b*64 + h*8)*NPP2 + (size_t)ty0*HP2 + tx0;
    for (int idx=t; idx<8*20*20; idx+=512){
        int cl = idx / 400; int rem = idx - cl*400; int r = rem/20, cc = rem - r*20;
        Qt[idx] = Qb[(size_t)cl*NPP2 + r*HP2 + cc];
    }
    // stage r halo(+-1)
    const float* rg = rfp + (size_t)(b*NH + h)*NPP + (size_t)ty0*HP + tx0;
    for (int idx=t; idx<18*18; idx+=512){
        int rr = idx / 18, cc = idx - rr*18;
        rt[rr*20 + cc] = rg[rr*HP + cc];
    }
    __syncthreads();

    const int c  = __builtin_amdgcn_readfirstlane(t >> 6);  // wave-uniform channel
    const int l  = t & 63;
    const int pr = l >> 2;          // pixel row 0..15
    const int pc = (l & 3) * 4;     // pixel col start 0,4,8,12

    const float* kvc = kvT2 + ((size_t)(b*NH + h)*DD + c*9)*96;  // rows u=0..8, stride 96

    float acc[9][4];
#pragma unroll
    for (int u=0;u<9;++u)
#pragma unroll
        for (int p=0;p<4;++p) acc[u][p]=0.f;

    for (int cl=0; cl<8; ++cl){
        // Q window: rows pr..pr+4, cols pc..pc+7
        float qw[5][8];
        const float* qb = &Qt[cl*400 + pr*20 + pc];
#pragma unroll
        for (int rr=0; rr<5; ++rr){
            float4 a0 = *(const float4*)(qb + rr*20);
            float4 a1 = *(const float4*)(qb + rr*20 + 4);
            qw[rr][0]=a0.x; qw[rr][1]=a0.y; qw[rr][2]=a0.z; qw[rr][3]=a0.w;
            qw[rr][4]=a1.x; qw[rr][5]=a1.y; qw[rr][6]=a1.z; qw[rr][7]=a1.w;
        }
#pragma unroll
        for (int u=0; u<9; ++u){
            const float* kr = kvc + u*96 + cl*12;   // wave-uniform address
            float kw[9];
#pragma unroll
            for (int i=0;i<9;++i) kw[i] = kr[i];
            const int iu = u/3, ju = u - iu*3;
#pragma unroll
            for (int w=0; w<9; ++w){
                const int rr = (w/3) - iu + 2;
                const int cc = (w%3) - ju + 2;
#pragma unroll
                for (int p=0;p<4;++p)
                    acc[u][p] += qw[rr][cc+p] * kw[w];
            }
        }
    }
    // r-weighted fold-gather
    float rw[3][6];
    const float* rb = &rt[pr*20 + pc];
#pragma unroll
    for (int rr=0; rr<3; ++rr)
#pragma unroll
        for (int j=0; j<6; ++j) rw[rr][j] = rb[rr*20 + j];
    float out[4];
#pragma unroll
    for (int p=0;p<4;++p) out[p]=0.f;
#pragma unroll
    for (int u=0; u<9; ++u){
        const int iu = u/3, ju = u - iu*3;
#pragma unroll
        for (int p=0;p<4;++p)
            out[p] += acc[u][p] * rw[2-iu][p+2-ju];
    }
    float4 o4 = make_float4(out[0], out[1], out[2], out[3]);
    *(float4*)(&folded[(size_t)(b*64 + h*8 + c)*NN + (ty0+pr)*WW + tx0 + pc]) = o4;
}

// ---------------- K6: y = conv3x3(folded/counts, w_proj) + b_proj ---------------------
__global__ __launch_bounds__(256) void k6_conv(const float* __restrict__ folded, const float* __restrict__ wt,
         const float* __restrict__ bproj, float* __restrict__ out){
    __shared__ __align__(16) float ut[8*18*12];   // [cil][rr(18)][cc(10), stride 12]
    const int t = threadIdx.x;
    const int tile = blockIdx.x;    // 0..127 : 8 row-tiles (16) x 16 col-tiles (8)
    const int b = blockIdx.y;
    const int ty0 = (tile >> 4)*16, tx0 = (tile & 15)*8;
    const int ocb = t & 15;         // 4 output channels
    const int s   = t >> 4;         // row 0..15
    float acc[4][8];
#pragma unroll
    for (int ol=0;ol<4;++ol)
#pragma unroll
        for (int p=0;p<8;++p) acc[ol][p]=0.f;
    const float4 bias = *(const float4*)(&bproj[ocb*4]);

    for (int ch=0; ch<8; ++ch){     // ci chunks of 8
        __syncthreads();
        for (int idx=t; idx<8*18*10; idx+=256){
            int cil = idx / 180; int rem = idx - cil*180; int rr = rem/10, cc = rem - rr*10;
            int iy = ty0 - 1 + rr, ix = tx0 - 1 + cc;
            float v = 0.f;
            if ((unsigned)iy < 128u && (unsigned)ix < 128u){
                int ry = 3 - (iy==0) - (iy==127);
                int rx = 3 - (ix==0) - (ix==127);
                v = folded[(size_t)(b*64 + ch*8 + cil)*NN + iy*WW + ix] / (float)(ry*rx);
            }
            ut[cil*216 + rr*12 + cc] = v;
        }
        __syncthreads();
        for (int cil=0; cil<8; ++cil){
            const int ci = ch*8 + cil;
            float uw[3][10];
            const float* ub = &ut[cil*216 + s*12];
#pragma unroll
            for (int dy=0;dy<3;++dy){
                float4 a0 = *(const float4*)(ub + dy*12);
                float4 a1 = *(const float4*)(ub + dy*12 + 4);
                float2 a2 = *(const float2*)(ub + dy*12 + 8);
                uw[dy][0]=a0.x; uw[dy][1]=a0.y; uw[dy][2]=a0.z; uw[dy][3]=a0.w;
                uw[dy][4]=a1.x; uw[dy][5]=a1.y; uw[dy][6]=a1.z; uw[dy][7]=a1.w;
                uw[dy][8]=a2.x; uw[dy][9]=a2.y;
            }
#pragma unroll
            for (int w=0;w<9;++w){
                const int dy = w/3, dx = w%3;
                float4 wv = *(const float4*)(&wt[(ci*9 + w)*64 + ocb*4]);
#pragma unroll
                for (int p=0;p<8;++p){
                    float u = uw[dy][p+dx];
                    acc[0][p] += wv.x*u;
                    acc[1][p] += wv.y*u;
                    acc[2][p] += wv.z*u;
                    acc[3][p] += wv.w*u;
                }
            }
        }
    }
    const int y = ty0 + s;
#pragma unroll
    for (int ol=0;ol<4;++ol){
        const int oc = ocb*4 + ol;
        float* dst = &out[(size_t)(b*64 + oc)*NN + y*WW + tx0];
        float bv = (ol==0)?bias.x:(ol==1)?bias.y:(ol==2)?bias.z:bias.w;
#pragma unroll
        for (int p=0;p<8;++p) dst[p] = acc[ol][p] + bv;
    }
}

extern "C" void kernel_launch(void* const* d_in, const int* in_sizes, int n_in,
                              void* d_out, int out_size, void* d_ws, size_t ws_size,
                              hipStream_t stream) {
    const float* x     = (const float*)d_in[0];
    const float* wqkv  = (const float*)d_in[1];
    const float* bqkv  = (const float*)d_in[2];
    const float* wproj = (const float*)d_in[3];
    const float* bproj = (const float*)d_in[4];
    float* out = (float*)d_out;
    float* ws  = (float*)d_ws;

    const size_t szQ2 = (size_t)BB*CC*NPP2;      // 4,460,544 floats (2-pad Q)
    const size_t szF  = (size_t)BB*CC*NPP;       // 4,326,400 floats (1-pad K/V)
    const size_t szR  = (size_t)BB*NH*NPP;       // 540,800 floats (1-pad r)
    float* Qp2    = ws;
    float* Kp     = Qp2 + szQ2;
    float* Vp     = Kp + szF;
    float* rfp    = Vp + szF;
    float* folded = rfp + szR;                   // B*C*N (written exclusively)
    float* kvT2   = folded + (size_t)BB*CC*NN;   // B*8*72 rows x 96 stride
    float* ksum   = kvT2 + (size_t)BB*NH*DD*96;  // B*8*72
    float* wt     = ksum + (size_t)BB*NH*DD;     // 64*9*64
    // total ~18.1M floats = ~72.4 MB of ws

    // zero the zero-padded fields (contiguous prefix): Qp2, Kp, Vp, rfp
    hipMemsetAsync(ws, 0, (szQ2 + 2*szF + szR)*sizeof(float), stream);

    k0_wt  <<<dim3(144),      256, 0, stream>>>(wproj, wt);
    k1_qkv <<<dim3(64, 3, 4), 256, 0, stream>>>(x, wqkv, bqkv, Qp2, Kp, Vp);
    k2_ksum<<<dim3(64, 4),    256, 0, stream>>>(Kp, ksum);
    k3_kv  <<<dim3(64, 8, 4), 256, 0, stream>>>(Kp, Vp, kvT2);
    k4_r   <<<dim3(64, 8, 4), 256, 0, stream>>>(Qp2, ksum, rfp);
    k5_attn<<<dim3(64, 8, 4), 512, 0, stream>>>(Qp2, kvT2, rfp, folded);
    k6_conv<<<dim3(128, 4),   256, 0, stream>>>(folded, wt, bproj, out);
}